// Round 2
// baseline (218.116 us; speedup 1.0000x reference)
//
#include <hip/hip_runtime.h>

// SMPL forward: B=512, V=6890, NB=10, NJ=24, 9 extra joints. Output fp32 (B, 6923, 3).

#define BATCH 512
#define NV 6890
#define NBD 10
#define NJ 24
#define NEXTRA 9
#define NOUT (NV + NJ + NEXTRA)   // 6923
#define VBLK ((NV + 255) / 256)   // 27 (precompute kernel grid)
#define BPB 4                     // batches per thread in LBS
#define VPT 2                     // vertices per thread in LBS
#define VB (256 * VPT)            // 512 verts per LBS block
#define NCHUNK 4                  // V-chunks in extra kernel
#define CHUNKV ((NV + NCHUNK - 1) / NCHUNK)  // 1723 -> use 1728 for stride alignment

__constant__ int c_par[NJ] = {-1,0,0,0,1,2,3,4,5,6,7,8,9,9,9,12,13,14,16,17,18,19,20,21};
__constant__ int c_lvl[NJ] = { 0,1,1,1,2,2,2,3,3,3,4,4,4, 4, 4, 5, 5, 5, 6, 6, 7, 7, 8, 8};

// ---------------------------------------------------------------------------
// Kernel A: batch-independent regressor precompute (unchanged from R1 — works).
// jtjs[j][0:3] = Jreg@v_template ; jtjs[j][3+k*10+l] = Jreg@shapedirs
// ---------------------------------------------------------------------------
__global__ __launch_bounds__(256) void precompute_kernel(
    const float* __restrict__ jreg,
    const float* __restrict__ smpl_t,
    const float* __restrict__ smil_t,
    const float* __restrict__ sdirs,
    const float* __restrict__ msc,
    float* __restrict__ jtjs)
{
    const int j = blockIdx.y;
    const int v = blockIdx.x * 256 + threadIdx.x;
    const float s = msc[0];

    float acc[33];
#pragma unroll
    for (int i = 0; i < 33; ++i) acc[i] = 0.f;

    if (v < NV) {
        const float w = jreg[j * NV + v];
#pragma unroll
        for (int k = 0; k < 3; ++k) {
            float vt = s * smpl_t[v * 3 + k] + (1.f - s) * smil_t[v * 3 + k];
            acc[k] = w * vt;
        }
        const float2* sd2 = (const float2*)(sdirs + (size_t)v * 30);
#pragma unroll
        for (int i = 0; i < 15; ++i) {
            float2 x = sd2[i];
            acc[3 + 2 * i]     = w * x.x;
            acc[3 + 2 * i + 1] = w * x.y;
        }
    }

#pragma unroll
    for (int i = 0; i < 33; ++i) {
        float x = acc[i];
        for (int off = 32; off; off >>= 1) x += __shfl_xor(x, off, 64);
        acc[i] = x;
    }

    __shared__ float red[4][33];
    const int lane = threadIdx.x & 63, wv = threadIdx.x >> 6;
    if (lane == 0) {
#pragma unroll
        for (int i = 0; i < 33; ++i) red[wv][i] = acc[i];
    }
    __syncthreads();
    if (threadIdx.x < 33) {
        float sum = red[0][threadIdx.x] + red[1][threadIdx.x]
                  + red[2][threadIdx.x] + red[3][threadIdx.x];
        atomicAdd(&jtjs[j * 33 + threadIdx.x], sum);
    }
}

// ---------------------------------------------------------------------------
// Kernel B: per-batch joints. Level-parallel kinematic chain (9 levels) instead
// of serial lane-0 compose. grid BATCH, block 64. Writes A[b,j] + posed joints.
// ---------------------------------------------------------------------------
__global__ __launch_bounds__(64) void joints_kernel(
    const float* __restrict__ betas,
    const float* __restrict__ body_pose,
    const float* __restrict__ glob_or,
    const float* __restrict__ transl,
    const float* __restrict__ jtjs,
    float* __restrict__ wsA,
    float* __restrict__ out)
{
    const int b = blockIdx.x;
    const int j = threadIdx.x;

    __shared__ float sJ[NJ][3];
    __shared__ float chain[NJ][12];
    __shared__ float sbeta[NBD + 1];

    if (threadIdx.x < NBD + 1) sbeta[threadIdx.x] = betas[b * (NBD + 1) + threadIdx.x];
    __syncthreads();

    float M[12];   // local [R | rel_t], registers
    if (j < NJ) {
        const float beta0 = sbeta[0];
#pragma unroll
        for (int k = 0; k < 3; ++k) {
            float a = jtjs[j * 33 + k];
#pragma unroll
            for (int l = 0; l < NBD; ++l) a = fmaf(sbeta[1 + l], jtjs[j * 33 + 3 + k * 10 + l], a);
            sJ[j][k] = a * beta0;
        }
        float rx, ry, rz;
        if (j == 0) {
            rx = glob_or[b * 3 + 0]; ry = glob_or[b * 3 + 1]; rz = glob_or[b * 3 + 2];
        } else {
            rx = body_pose[b * 69 + (j - 1) * 3 + 0];
            ry = body_pose[b * 69 + (j - 1) * 3 + 1];
            rz = body_pose[b * 69 + (j - 1) * 3 + 2];
        }
        float ex = rx + 1e-8f, ey = ry + 1e-8f, ez = rz + 1e-8f;
        float ang = sqrtf(ex * ex + ey * ey + ez * ez);
        float inv = 1.f / ang;
        float ax = rx * inv, ay = ry * inv, az = rz * inv;
        float c = cosf(ang), s = sinf(ang), t = 1.f - c;
        M[0]  = 1.f + t * (-(ay * ay + az * az));
        M[1]  = -s * az + t * (ax * ay);
        M[2]  =  s * ay + t * (ax * az);
        M[4]  =  s * az + t * (ax * ay);
        M[5]  = 1.f + t * (-(ax * ax + az * az));
        M[6]  = -s * ax + t * (ay * az);
        M[8]  = -s * ay + t * (ax * az);
        M[9]  =  s * ax + t * (ay * az);
        M[10] = 1.f + t * (-(ax * ax + ay * ay));
    }
    __syncthreads();
    if (j < NJ) {
        const int p = c_par[j];
        float t0 = sJ[j][0], t1 = sJ[j][1], t2 = sJ[j][2];
        if (p >= 0) { t0 -= sJ[p][0]; t1 -= sJ[p][1]; t2 -= sJ[p][2]; }
        M[3] = t0; M[7] = t1; M[11] = t2;
        if (j == 0) {
#pragma unroll
            for (int k = 0; k < 12; ++k) chain[0][k] = M[k];
        }
    }
    __syncthreads();
    // level-parallel compose: chain[j] = chain[parent] * M[j]
#pragma unroll
    for (int level = 1; level <= 8; ++level) {
        if (j < NJ && c_lvl[j] == level) {
            const int p = c_par[j];
            float P[12];
#pragma unroll
            for (int k = 0; k < 12; ++k) P[k] = chain[p][k];
            float C[12];
#pragma unroll
            for (int r = 0; r < 3; ++r) {
#pragma unroll
                for (int col = 0; col < 4; ++col) {
                    float acc = (col == 3) ? P[r * 4 + 3] : 0.f;
#pragma unroll
                    for (int q = 0; q < 3; ++q) acc = fmaf(P[r * 4 + q], M[q * 4 + col], acc);
                    C[r * 4 + col] = acc;
                }
            }
#pragma unroll
            for (int k = 0; k < 12; ++k) chain[j][k] = C[k];
        }
        __syncthreads();
    }
    if (j < NJ) {
        float A[12];
#pragma unroll
        for (int k = 0; k < 12; ++k) A[k] = chain[j][k];
        const float c0 = A[3], c1 = A[7], c2 = A[11];
        const float j0 = sJ[j][0], j1 = sJ[j][1], j2 = sJ[j][2];
        A[3]  = c0 - (A[0] * j0 + A[1] * j1 + A[2]  * j2);
        A[7]  = c1 - (A[4] * j0 + A[5] * j1 + A[6]  * j2);
        A[11] = c2 - (A[8] * j0 + A[9] * j1 + A[10] * j2);
#pragma unroll
        for (int k = 0; k < 12; ++k) wsA[((size_t)b * NJ + j) * 12 + k] = A[k];
        const float tx = transl[b * 3 + 0], ty = transl[b * 3 + 1], tz = transl[b * 3 + 2];
        const size_t o = ((size_t)b * NOUT + NV + j) * 3;
        out[o + 0] = c0 + tx; out[o + 1] = c1 + ty; out[o + 2] = c2 + tz;
    }
}

// ---------------------------------------------------------------------------
// Kernel C: LBS skinning. VPT=2 vertices/thread so each scalar A dword feeds
// 2 FMAs (halves the s_load stream per unit work, doubles per-wave ILP).
// grid (14, BATCH/BPB), block 256.
// ---------------------------------------------------------------------------
__global__ __launch_bounds__(256) void lbs_kernel(
    const float* __restrict__ betas,
    const float* __restrict__ transl,
    const float* __restrict__ msc,
    const float* __restrict__ smpl_t,
    const float* __restrict__ smil_t,
    const float* __restrict__ sdirs,
    const float* __restrict__ lbsw,
    const float* __restrict__ wsA,
    float* __restrict__ out)
{
    const int vbase = blockIdx.x * VB + threadIdx.x;
    const int b0 = blockIdx.y * BPB;
    const float s = msc[0];

    int   vidx[VPT];
    bool  valid[VPT];
#pragma unroll
    for (int u = 0; u < VPT; ++u) {
        int v = vbase + u * 256;
        valid[u] = v < NV;
        vidx[u] = valid[u] ? v : NV - 1;
    }

    float vt[VPT][3];
    float sd[VPT][30];
    float w[VPT][NJ];
#pragma unroll
    for (int u = 0; u < VPT; ++u) {
        const int vc = vidx[u];
#pragma unroll
        for (int k = 0; k < 3; ++k)
            vt[u][k] = s * smpl_t[vc * 3 + k] + (1.f - s) * smil_t[vc * 3 + k];
        const float2* sd2 = (const float2*)(sdirs + (size_t)vc * 30);
#pragma unroll
        for (int i = 0; i < 15; ++i) {
            float2 x = sd2[i];
            sd[u][2 * i] = x.x; sd[u][2 * i + 1] = x.y;
        }
        const float4* w4 = (const float4*)(lbsw + (size_t)vc * NJ);
#pragma unroll
        for (int i = 0; i < 6; ++i) {
            float4 x = w4[i];
            w[u][4 * i] = x.x; w[u][4 * i + 1] = x.y; w[u][4 * i + 2] = x.z; w[u][4 * i + 3] = x.w;
        }
    }

#pragma unroll
    for (int bb = 0; bb < BPB; ++bb) {
        const int b = b0 + bb;
        const float* __restrict__ Bb = betas + b * (NBD + 1);     // uniform → s_load
        const float* __restrict__ Ab = wsA + (size_t)b * NJ * 12; // uniform → s_load

        float vs[VPT][3];
#pragma unroll
        for (int u = 0; u < VPT; ++u) {
#pragma unroll
            for (int k = 0; k < 3; ++k) {
                float a = vt[u][k];
#pragma unroll
                for (int l = 0; l < NBD; ++l) a = fmaf(Bb[1 + l], sd[u][k * 10 + l], a);
                vs[u][k] = a * Bb[0];
            }
        }

        float T[VPT][12];
#pragma unroll
        for (int u = 0; u < VPT; ++u)
#pragma unroll
            for (int k = 0; k < 12; ++k) T[u][k] = 0.f;

#pragma unroll 4
        for (int jj = 0; jj < NJ; ++jj) {
            float a[12];
#pragma unroll
            for (int k = 0; k < 12; ++k) a[k] = Ab[jj * 12 + k];
#pragma unroll
            for (int u = 0; u < VPT; ++u) {
                const float ww = w[u][jj];
#pragma unroll
                for (int k = 0; k < 12; ++k) T[u][k] = fmaf(ww, a[k], T[u][k]);
            }
        }

        const float tx = transl[b * 3 + 0], ty = transl[b * 3 + 1], tz = transl[b * 3 + 2];
#pragma unroll
        for (int u = 0; u < VPT; ++u) {
            if (valid[u]) {
                const size_t o = ((size_t)b * NOUT + vidx[u]) * 3;
                out[o + 0] = fmaf(T[u][0], vs[u][0], fmaf(T[u][1], vs[u][1], fmaf(T[u][2],  vs[u][2], T[u][3])))  + tx;
                out[o + 1] = fmaf(T[u][4], vs[u][0], fmaf(T[u][5], vs[u][1], fmaf(T[u][6],  vs[u][2], T[u][7])))  + ty;
                out[o + 2] = fmaf(T[u][8], vs[u][0], fmaf(T[u][9], vs[u][1], fmaf(T[u][10], vs[u][2], T[u][11]))) + tz;
            }
        }
    }
}

// ---------------------------------------------------------------------------
// Kernel D: extra joints, partial over V-chunks. grid (BATCH, NCHUNK), block 256.
// part[(b*NCHUNK+c)*27 + i] = partial sums. Finalize kernel combines.
// ---------------------------------------------------------------------------
__global__ __launch_bounds__(256) void extra_kernel(
    const float* __restrict__ jre,
    const float* __restrict__ out,
    float* __restrict__ part)
{
    const int b = blockIdx.x;
    const int c = blockIdx.y;
    const int v0 = c * CHUNKV;
    const int v1 = min(NV, v0 + CHUNKV);
    const float* vb = out + (size_t)b * NOUT * 3;

    float acc[27];
#pragma unroll
    for (int i = 0; i < 27; ++i) acc[i] = 0.f;

    for (int v = v0 + threadIdx.x; v < v1; v += 256) {
        const float x = vb[v * 3 + 0], y = vb[v * 3 + 1], z = vb[v * 3 + 2];
#pragma unroll
        for (int e = 0; e < NEXTRA; ++e) {
            const float we = jre[e * NV + v];
            acc[e * 3 + 0] = fmaf(we, x, acc[e * 3 + 0]);
            acc[e * 3 + 1] = fmaf(we, y, acc[e * 3 + 1]);
            acc[e * 3 + 2] = fmaf(we, z, acc[e * 3 + 2]);
        }
    }

#pragma unroll
    for (int i = 0; i < 27; ++i) {
        float x = acc[i];
        for (int off = 32; off; off >>= 1) x += __shfl_xor(x, off, 64);
        acc[i] = x;
    }
    __shared__ float red[4][27];
    const int lane = threadIdx.x & 63, wv = threadIdx.x >> 6;
    if (lane == 0) {
#pragma unroll
        for (int i = 0; i < 27; ++i) red[wv][i] = acc[i];
    }
    __syncthreads();
    if (threadIdx.x < 27) {
        part[((size_t)b * NCHUNK + c) * 27 + threadIdx.x] =
            red[0][threadIdx.x] + red[1][threadIdx.x] + red[2][threadIdx.x] + red[3][threadIdx.x];
    }
}

__global__ __launch_bounds__(256) void extra_fin_kernel(
    const float* __restrict__ part,
    float* __restrict__ out)
{
    const int idx = blockIdx.x * 256 + threadIdx.x;
    if (idx < BATCH * 27) {
        const int b = idx / 27, i = idx % 27;
        float sum = 0.f;
#pragma unroll
        for (int c = 0; c < NCHUNK; ++c) sum += part[((size_t)b * NCHUNK + c) * 27 + i];
        out[((size_t)b * NOUT + NV + NJ) * 3 + i] = sum;
    }
}

// ---------------------------------------------------------------------------
extern "C" void kernel_launch(void* const* d_in, const int* in_sizes, int n_in,
                              void* d_out, int out_size, void* d_ws, size_t ws_size,
                              hipStream_t stream) {
    const float* betas     = (const float*)d_in[0];
    const float* body_pose = (const float*)d_in[1];
    const float* glob_or   = (const float*)d_in[2];
    const float* transl    = (const float*)d_in[3];
    const float* msc       = (const float*)d_in[4];
    const float* smpl_t    = (const float*)d_in[5];
    const float* smil_t    = (const float*)d_in[6];
    const float* sdirs     = (const float*)d_in[7];
    const float* jreg      = (const float*)d_in[8];
    const float* lbsw      = (const float*)d_in[9];
    const float* jre       = (const float*)d_in[10];

    float* out  = (float*)d_out;
    float* ws   = (float*)d_ws;
    float* jtjs = ws;                      // 24*33 = 792 floats
    float* wsA  = ws + 792;                // 512*24*12 = 147456 floats
    float* part = wsA + (size_t)BATCH * NJ * 12;  // 512*4*27 = 55296 floats

    hipMemsetAsync(jtjs, 0, NJ * 33 * sizeof(float), stream);

    dim3 gA(VBLK, NJ);
    precompute_kernel<<<gA, 256, 0, stream>>>(jreg, smpl_t, smil_t, sdirs, msc, jtjs);

    joints_kernel<<<BATCH, 64, 0, stream>>>(betas, body_pose, glob_or, transl, jtjs, wsA, out);

    dim3 gC((NV + VB - 1) / VB, BATCH / BPB);
    lbs_kernel<<<gC, 256, 0, stream>>>(betas, transl, msc, smpl_t, smil_t, sdirs, lbsw, wsA, out);

    dim3 gD(BATCH, NCHUNK);
    extra_kernel<<<gD, 256, 0, stream>>>(jre, out, part);

    extra_fin_kernel<<<(BATCH * 27 + 255) / 256, 256, 0, stream>>>(part, out);
}

// Round 3
// 197.973 us; speedup vs baseline: 1.1018x; 1.1018x over previous
//
#include <hip/hip_runtime.h>

// SMPL forward: B=512, V=6890, NB=10, NJ=24, 9 extra joints. Output fp32 (B, 6923, 3).

#define BATCH 512
#define NV 6890
#define NBD 10
#define NJ 24
#define NEXTRA 9
#define NOUT (NV + NJ + NEXTRA)   // 6923
#define VBLK ((NV + 255) / 256)   // 27
#define BPB 4                     // batches per thread in LBS (processed as 2 pairs)
#define NCHUNK 8                  // V-chunks in extra kernel
#define CHUNKV ((NV + NCHUNK - 1) / NCHUNK)  // 862

__constant__ int c_par[NJ] = {-1,0,0,0,1,2,3,4,5,6,7,8,9,9,9,12,13,14,16,17,18,19,20,21};
__constant__ int c_lvl[NJ] = { 0,1,1,1,2,2,2,3,3,3,4,4,4, 4, 4, 5, 5, 5, 6, 6, 7, 7, 8, 8};

// ---------------------------------------------------------------------------
// Kernel A: batch-independent regressor precompute (unchanged — works).
// jtjs[j][0:3] = Jreg@v_template ; jtjs[j][3+k*10+l] = Jreg@shapedirs
// ---------------------------------------------------------------------------
__global__ __launch_bounds__(256) void precompute_kernel(
    const float* __restrict__ jreg,
    const float* __restrict__ smpl_t,
    const float* __restrict__ smil_t,
    const float* __restrict__ sdirs,
    const float* __restrict__ msc,
    float* __restrict__ jtjs)
{
    const int j = blockIdx.y;
    const int v = blockIdx.x * 256 + threadIdx.x;
    const float s = msc[0];

    float acc[33];
#pragma unroll
    for (int i = 0; i < 33; ++i) acc[i] = 0.f;

    if (v < NV) {
        const float w = jreg[j * NV + v];
#pragma unroll
        for (int k = 0; k < 3; ++k) {
            float vt = s * smpl_t[v * 3 + k] + (1.f - s) * smil_t[v * 3 + k];
            acc[k] = w * vt;
        }
        const float2* sd2 = (const float2*)(sdirs + (size_t)v * 30);
#pragma unroll
        for (int i = 0; i < 15; ++i) {
            float2 x = sd2[i];
            acc[3 + 2 * i]     = w * x.x;
            acc[3 + 2 * i + 1] = w * x.y;
        }
    }

#pragma unroll
    for (int i = 0; i < 33; ++i) {
        float x = acc[i];
        for (int off = 32; off; off >>= 1) x += __shfl_xor(x, off, 64);
        acc[i] = x;
    }

    __shared__ float red[4][33];
    const int lane = threadIdx.x & 63, wv = threadIdx.x >> 6;
    if (lane == 0) {
#pragma unroll
        for (int i = 0; i < 33; ++i) red[wv][i] = acc[i];
    }
    __syncthreads();
    if (threadIdx.x < 33) {
        float sum = red[0][threadIdx.x] + red[1][threadIdx.x]
                  + red[2][threadIdx.x] + red[3][threadIdx.x];
        atomicAdd(&jtjs[j * 33 + threadIdx.x], sum);
    }
}

// ---------------------------------------------------------------------------
// Kernel B: per-batch joints, level-parallel chain (unchanged — works).
// ---------------------------------------------------------------------------
__global__ __launch_bounds__(64) void joints_kernel(
    const float* __restrict__ betas,
    const float* __restrict__ body_pose,
    const float* __restrict__ glob_or,
    const float* __restrict__ transl,
    const float* __restrict__ jtjs,
    float* __restrict__ wsA,
    float* __restrict__ out)
{
    const int b = blockIdx.x;
    const int j = threadIdx.x;

    __shared__ float sJ[NJ][3];
    __shared__ float chain[NJ][12];
    __shared__ float sbeta[NBD + 1];

    if (threadIdx.x < NBD + 1) sbeta[threadIdx.x] = betas[b * (NBD + 1) + threadIdx.x];
    __syncthreads();

    float M[12];
    if (j < NJ) {
        const float beta0 = sbeta[0];
#pragma unroll
        for (int k = 0; k < 3; ++k) {
            float a = jtjs[j * 33 + k];
#pragma unroll
            for (int l = 0; l < NBD; ++l) a = fmaf(sbeta[1 + l], jtjs[j * 33 + 3 + k * 10 + l], a);
            sJ[j][k] = a * beta0;
        }
        float rx, ry, rz;
        if (j == 0) {
            rx = glob_or[b * 3 + 0]; ry = glob_or[b * 3 + 1]; rz = glob_or[b * 3 + 2];
        } else {
            rx = body_pose[b * 69 + (j - 1) * 3 + 0];
            ry = body_pose[b * 69 + (j - 1) * 3 + 1];
            rz = body_pose[b * 69 + (j - 1) * 3 + 2];
        }
        float ex = rx + 1e-8f, ey = ry + 1e-8f, ez = rz + 1e-8f;
        float ang = sqrtf(ex * ex + ey * ey + ez * ez);
        float inv = 1.f / ang;
        float ax = rx * inv, ay = ry * inv, az = rz * inv;
        float c = cosf(ang), s = sinf(ang), t = 1.f - c;
        M[0]  = 1.f + t * (-(ay * ay + az * az));
        M[1]  = -s * az + t * (ax * ay);
        M[2]  =  s * ay + t * (ax * az);
        M[4]  =  s * az + t * (ax * ay);
        M[5]  = 1.f + t * (-(ax * ax + az * az));
        M[6]  = -s * ax + t * (ay * az);
        M[8]  = -s * ay + t * (ax * az);
        M[9]  =  s * ax + t * (ay * az);
        M[10] = 1.f + t * (-(ax * ax + ay * ay));
    }
    __syncthreads();
    if (j < NJ) {
        const int p = c_par[j];
        float t0 = sJ[j][0], t1 = sJ[j][1], t2 = sJ[j][2];
        if (p >= 0) { t0 -= sJ[p][0]; t1 -= sJ[p][1]; t2 -= sJ[p][2]; }
        M[3] = t0; M[7] = t1; M[11] = t2;
        if (j == 0) {
#pragma unroll
            for (int k = 0; k < 12; ++k) chain[0][k] = M[k];
        }
    }
    __syncthreads();
#pragma unroll
    for (int level = 1; level <= 8; ++level) {
        if (j < NJ && c_lvl[j] == level) {
            const int p = c_par[j];
            float P[12];
#pragma unroll
            for (int k = 0; k < 12; ++k) P[k] = chain[p][k];
            float C[12];
#pragma unroll
            for (int r = 0; r < 3; ++r) {
#pragma unroll
                for (int col = 0; col < 4; ++col) {
                    float acc = (col == 3) ? P[r * 4 + 3] : 0.f;
#pragma unroll
                    for (int q = 0; q < 3; ++q) acc = fmaf(P[r * 4 + q], M[q * 4 + col], acc);
                    C[r * 4 + col] = acc;
                }
            }
#pragma unroll
            for (int k = 0; k < 12; ++k) chain[j][k] = C[k];
        }
        __syncthreads();
    }
    if (j < NJ) {
        float A[12];
#pragma unroll
        for (int k = 0; k < 12; ++k) A[k] = chain[j][k];
        const float c0 = A[3], c1 = A[7], c2 = A[11];
        const float j0 = sJ[j][0], j1 = sJ[j][1], j2 = sJ[j][2];
        A[3]  = c0 - (A[0] * j0 + A[1] * j1 + A[2]  * j2);
        A[7]  = c1 - (A[4] * j0 + A[5] * j1 + A[6]  * j2);
        A[11] = c2 - (A[8] * j0 + A[9] * j1 + A[10] * j2);
#pragma unroll
        for (int k = 0; k < 12; ++k) wsA[((size_t)b * NJ + j) * 12 + k] = A[k];
        const float tx = transl[b * 3 + 0], ty = transl[b * 3 + 1], tz = transl[b * 3 + 2];
        const size_t o = ((size_t)b * NOUT + NV + j) * 3;
        out[o + 0] = c0 + tx; out[o + 1] = c1 + ty; out[o + 2] = c2 + tz;
    }
}

// ---------------------------------------------------------------------------
// Kernel C: LBS skinning, v3.
// VPT=1 (round-2 VPT=2 spilled to scratch: WRITE 42->128 MB). Instead, ILP comes
// from interleaving a BATCH PAIR: two independent scalar A-load chains + 2x FMA
// per loaded A dword. Joint loop fully unrolled so the compiler pipelines
// s_loads to SGPR budget depth instead of stalling every 4 joints.
// __launch_bounds__(256,4): VGPR cap 128 (est ~110), 4 blocks/CU.
// grid (27, BATCH/BPB), block 256.
// ---------------------------------------------------------------------------
__global__ __launch_bounds__(256, 4) void lbs_kernel(
    const float* __restrict__ betas,
    const float* __restrict__ transl,
    const float* __restrict__ msc,
    const float* __restrict__ smpl_t,
    const float* __restrict__ smil_t,
    const float* __restrict__ sdirs,
    const float* __restrict__ lbsw,
    const float* __restrict__ wsA,
    float* __restrict__ out)
{
    const int v = blockIdx.x * 256 + threadIdx.x;
    const bool valid = v < NV;
    const int vc = valid ? v : NV - 1;
    const int b0 = blockIdx.y * BPB;
    const float s = msc[0];

    // per-vertex, batch-independent data (57 floats -> registers, no spill at cap 128)
    float vt[3];
#pragma unroll
    for (int k = 0; k < 3; ++k)
        vt[k] = s * smpl_t[vc * 3 + k] + (1.f - s) * smil_t[vc * 3 + k];

    float sd[30];
    {
        const float2* sd2 = (const float2*)(sdirs + (size_t)vc * 30);
#pragma unroll
        for (int i = 0; i < 15; ++i) { float2 x = sd2[i]; sd[2 * i] = x.x; sd[2 * i + 1] = x.y; }
    }
    float w[NJ];
    {
        const float4* w4 = (const float4*)(lbsw + (size_t)vc * NJ);
#pragma unroll
        for (int i = 0; i < 6; ++i) {
            float4 x = w4[i];
            w[4 * i] = x.x; w[4 * i + 1] = x.y; w[4 * i + 2] = x.z; w[4 * i + 3] = x.w;
        }
    }

#pragma unroll
    for (int pp = 0; pp < BPB / 2; ++pp) {
        const int b = b0 + 2 * pp;
        const float* __restrict__ B0 = betas + b * (NBD + 1);       // uniform → s_load
        const float* __restrict__ B1 = B0 + (NBD + 1);
        const float* __restrict__ A0 = wsA + (size_t)b * NJ * 12;   // uniform → s_load
        const float* __restrict__ A1 = A0 + NJ * 12;

        // v_shaped for both batches of the pair (interleaved chains)
        float vs0[3], vs1[3];
#pragma unroll
        for (int k = 0; k < 3; ++k) {
            float a0 = vt[k], a1 = vt[k];
#pragma unroll
            for (int l = 0; l < NBD; ++l) {
                const float sdl = sd[k * 10 + l];
                a0 = fmaf(B0[1 + l], sdl, a0);
                a1 = fmaf(B1[1 + l], sdl, a1);
            }
            vs0[k] = a0 * B0[0];
            vs1[k] = a1 * B1[0];
        }

        // T = sum_j w_j * A_j for both batches — fully unrolled, 2 indep chains
        float T0[12], T1[12];
#pragma unroll
        for (int k = 0; k < 12; ++k) { T0[k] = 0.f; T1[k] = 0.f; }
#pragma unroll
        for (int jj = 0; jj < NJ; ++jj) {
            const float ww = w[jj];
#pragma unroll
            for (int k = 0; k < 12; ++k) {
                T0[k] = fmaf(ww, A0[jj * 12 + k], T0[k]);
                T1[k] = fmaf(ww, A1[jj * 12 + k], T1[k]);
            }
        }

        if (valid) {
            const float tx0 = transl[b * 3 + 0], ty0 = transl[b * 3 + 1], tz0 = transl[b * 3 + 2];
            const float tx1 = transl[b * 3 + 3], ty1 = transl[b * 3 + 4], tz1 = transl[b * 3 + 5];
            const size_t o0 = ((size_t)b * NOUT + v) * 3;
            const size_t o1 = o0 + (size_t)NOUT * 3;
            out[o0 + 0] = fmaf(T0[0], vs0[0], fmaf(T0[1], vs0[1], fmaf(T0[2],  vs0[2], T0[3])))  + tx0;
            out[o0 + 1] = fmaf(T0[4], vs0[0], fmaf(T0[5], vs0[1], fmaf(T0[6],  vs0[2], T0[7])))  + ty0;
            out[o0 + 2] = fmaf(T0[8], vs0[0], fmaf(T0[9], vs0[1], fmaf(T0[10], vs0[2], T0[11]))) + tz0;
            out[o1 + 0] = fmaf(T1[0], vs1[0], fmaf(T1[1], vs1[1], fmaf(T1[2],  vs1[2], T1[3])))  + tx1;
            out[o1 + 1] = fmaf(T1[4], vs1[0], fmaf(T1[5], vs1[1], fmaf(T1[6],  vs1[2], T1[7])))  + ty1;
            out[o1 + 2] = fmaf(T1[8], vs1[0], fmaf(T1[9], vs1[1], fmaf(T1[10], vs1[2], T1[11]))) + tz1;
        }
    }
}

// ---------------------------------------------------------------------------
// Kernel D: extra joints partials over V-chunks. grid (BATCH, NCHUNK), block 256.
// ---------------------------------------------------------------------------
__global__ __launch_bounds__(256) void extra_kernel(
    const float* __restrict__ jre,
    const float* __restrict__ out,
    float* __restrict__ part)
{
    const int b = blockIdx.x;
    const int c = blockIdx.y;
    const int v0 = c * CHUNKV;
    const int v1 = min(NV, v0 + CHUNKV);
    const float* vb = out + (size_t)b * NOUT * 3;

    float acc[27];
#pragma unroll
    for (int i = 0; i < 27; ++i) acc[i] = 0.f;

    for (int v = v0 + threadIdx.x; v < v1; v += 256) {
        const float x = vb[v * 3 + 0], y = vb[v * 3 + 1], z = vb[v * 3 + 2];
#pragma unroll
        for (int e = 0; e < NEXTRA; ++e) {
            const float we = jre[e * NV + v];
            acc[e * 3 + 0] = fmaf(we, x, acc[e * 3 + 0]);
            acc[e * 3 + 1] = fmaf(we, y, acc[e * 3 + 1]);
            acc[e * 3 + 2] = fmaf(we, z, acc[e * 3 + 2]);
        }
    }

#pragma unroll
    for (int i = 0; i < 27; ++i) {
        float x = acc[i];
        for (int off = 32; off; off >>= 1) x += __shfl_xor(x, off, 64);
        acc[i] = x;
    }
    __shared__ float red[4][27];
    const int lane = threadIdx.x & 63, wv = threadIdx.x >> 6;
    if (lane == 0) {
#pragma unroll
        for (int i = 0; i < 27; ++i) red[wv][i] = acc[i];
    }
    __syncthreads();
    if (threadIdx.x < 27) {
        part[((size_t)b * NCHUNK + c) * 27 + threadIdx.x] =
            red[0][threadIdx.x] + red[1][threadIdx.x] + red[2][threadIdx.x] + red[3][threadIdx.x];
    }
}

__global__ __launch_bounds__(256) void extra_fin_kernel(
    const float* __restrict__ part,
    float* __restrict__ out)
{
    const int idx = blockIdx.x * 256 + threadIdx.x;
    if (idx < BATCH * 27) {
        const int b = idx / 27, i = idx % 27;
        float sum = 0.f;
#pragma unroll
        for (int c = 0; c < NCHUNK; ++c) sum += part[((size_t)b * NCHUNK + c) * 27 + i];
        out[((size_t)b * NOUT + NV + NJ) * 3 + i] = sum;
    }
}

// ---------------------------------------------------------------------------
extern "C" void kernel_launch(void* const* d_in, const int* in_sizes, int n_in,
                              void* d_out, int out_size, void* d_ws, size_t ws_size,
                              hipStream_t stream) {
    const float* betas     = (const float*)d_in[0];
    const float* body_pose = (const float*)d_in[1];
    const float* glob_or   = (const float*)d_in[2];
    const float* transl    = (const float*)d_in[3];
    const float* msc       = (const float*)d_in[4];
    const float* smpl_t    = (const float*)d_in[5];
    const float* smil_t    = (const float*)d_in[6];
    const float* sdirs     = (const float*)d_in[7];
    const float* jreg      = (const float*)d_in[8];
    const float* lbsw      = (const float*)d_in[9];
    const float* jre       = (const float*)d_in[10];

    float* out  = (float*)d_out;
    float* ws   = (float*)d_ws;
    float* jtjs = ws;                              // 24*33 = 792 floats
    float* wsA  = ws + 792;                        // 512*24*12 = 147456 floats
    float* part = wsA + (size_t)BATCH * NJ * 12;   // 512*8*27 = 110592 floats

    hipMemsetAsync(jtjs, 0, NJ * 33 * sizeof(float), stream);

    dim3 gA(VBLK, NJ);
    precompute_kernel<<<gA, 256, 0, stream>>>(jreg, smpl_t, smil_t, sdirs, msc, jtjs);

    joints_kernel<<<BATCH, 64, 0, stream>>>(betas, body_pose, glob_or, transl, jtjs, wsA, out);

    dim3 gC(VBLK, BATCH / BPB);
    lbs_kernel<<<gC, 256, 0, stream>>>(betas, transl, msc, smpl_t, smil_t, sdirs, lbsw, wsA, out);

    dim3 gD(BATCH, NCHUNK);
    extra_kernel<<<gD, 256, 0, stream>>>(jre, out, part);

    extra_fin_kernel<<<(BATCH * 27 + 255) / 256, 256, 0, stream>>>(part, out);
}